// Round 2
// baseline (6176.321 us; speedup 1.0000x reference)
//
#include <hip/hip_runtime.h>
#include <hip/hip_bf16.h>

namespace {

constexpr int B = 2, S = 2048, E = 512, H = 8, D = 64, HD = 512;
constexpr float NEG = -1e10f;

// C[row, col] = sum_k A[row*512+k] * W[k*512+col]   (all fp32)
__global__ __launch_bounds__(256) void proj_kernel(
    const float* __restrict__ A, const float* __restrict__ W, float* __restrict__ C) {
  __shared__ float arow[512];
  const int row = blockIdx.y;
  const int col = blockIdx.x * 256 + threadIdx.x;
  for (int e = threadIdx.x; e < 512; e += 256) arow[e] = A[(size_t)row * 512 + e];
  __syncthreads();
  float acc = 0.f;
#pragma unroll 8
  for (int e = 0; e < 512; ++e) acc += arow[e] * W[(size_t)e * 512 + col];
  C[(size_t)row * 512 + col] = acc;
}

// One block (4 waves) per (b, h, q) row: scores -> mask -> softmax -> P@V
__global__ __launch_bounds__(256) void attn_kernel(
    const float* __restrict__ Q, const float* __restrict__ K,
    const float* __restrict__ V, const int* __restrict__ mask,
    float* __restrict__ O) {
  __shared__ float qv[D];
  __shared__ float sc[S];
  __shared__ float red[256];

  const int bid = blockIdx.x;            // ((b*H)+h)*S + q
  const int q = bid & (S - 1);
  const int h = (bid >> 11) & (H - 1);
  const int b = bid >> 14;
  const int tid = threadIdx.x;
  const int lane = tid & 63;
  const int w = tid >> 6;

  if (tid < D) qv[tid] = Q[((size_t)(b * S + q)) * HD + h * D + tid];
  __syncthreads();
  const float qr = qv[lane];

  // scores: wave w handles keys k = w, w+4, ...; lane = d
  const float* Kb = K + ((size_t)b * S * H + h) * D;   // + k*HD + d
  const int* mrow = mask + ((size_t)b * S + q) * S;
  for (int k = w; k < S; k += 4) {
    float x = qr * Kb[(size_t)k * HD + lane];
#pragma unroll
    for (int off = 32; off; off >>= 1) x += __shfl_xor(x, off);
    if (lane == 0) sc[k] = mrow[k] ? NEG : x * 0.125f;  // 1/sqrt(64)
  }
  __syncthreads();

  // softmax over sc[0..S)
  float m = -INFINITY;
  for (int k = tid; k < S; k += 256) m = fmaxf(m, sc[k]);
  red[tid] = m;
  __syncthreads();
  for (int s2 = 128; s2; s2 >>= 1) {
    if (tid < s2) red[tid] = fmaxf(red[tid], red[tid + s2]);
    __syncthreads();
  }
  const float mx = red[0];
  __syncthreads();
  float sum = 0.f;
  for (int k = tid; k < S; k += 256) {
    float p = __expf(sc[k] - mx);
    sc[k] = p;
    sum += p;
  }
  red[tid] = sum;
  __syncthreads();
  for (int s2 = 128; s2; s2 >>= 1) {
    if (tid < s2) red[tid] += red[tid + s2];
    __syncthreads();
  }
  const float inv = 1.f / red[0];
  __syncthreads();

  // P @ V: wave w covers k in [w*512, w*512+512), lane = d
  const float* Vb = V + ((size_t)b * S * H + h) * D;
  float acc = 0.f;
  const int k0 = w * 512;
  for (int k = k0; k < k0 + 512; ++k) acc += sc[k] * Vb[(size_t)k * HD + lane];
  red[w * 64 + lane] = acc;
  __syncthreads();
  if (tid < 64) {
    float r = (red[tid] + red[64 + tid] + red[128 + tid] + red[192 + tid]) * inv;
    O[((size_t)b * S + q) * HD + h * D + tid] = r;
  }
}

}  // namespace

extern "C" void kernel_launch(void* const* d_in, const int* in_sizes, int n_in,
                              void* d_out, int out_size, void* d_ws, size_t ws_size,
                              hipStream_t stream) {
  const float* inputs = (const float*)d_in[0];   // (B,S,E)
  const float* keys   = (const float*)d_in[1];   // (B,S,H,D)
  const float* values = (const float*)d_in[2];   // (B,S,H,D)
  const float* wq     = (const float*)d_in[3];   // (E, HD)
  const float* wo     = (const float*)d_in[4];   // (HD, E)
  const int*   maskp  = (const int*)d_in[5];     // (B,S,S) bool as int32
  float* out = (float*)d_out;                    // (B,S,E)

  float* Qf   = (float*)d_ws;                    // B*S*HD fp32 = 8 MB
  float* attn = Qf + (size_t)B * S * HD;         // B*S*HD fp32 = 8 MB

  dim3 blk(256);
  proj_kernel<<<dim3(HD / 256, B * S), blk, 0, stream>>>(inputs, wq, Qf);
  attn_kernel<<<dim3(B * H * S), blk, 0, stream>>>(Qf, keys, values, maskp, attn);
  proj_kernel<<<dim3(E / 256, B * S), blk, 0, stream>>>(attn, wo, out);
}

// Round 4
// 495.945 us; speedup vs baseline: 12.4536x; 12.4536x over previous
//
#include <hip/hip_runtime.h>
#include <hip/hip_bf16.h>

namespace {

constexpr int B = 2, S = 2048, E = 512, H = 8, D = 64, HD = 512;
constexpr float NEG = -1e10f;
constexpr float SCALE = 0.125f;  // 1/sqrt(64)
constexpr int LDK = 72;          // padded row stride in bf16: 144 B (16B-aligned, bank-step 4)

typedef __attribute__((ext_vector_type(8))) short bf16x8;
typedef __attribute__((ext_vector_type(4))) float f32x4;

__device__ __forceinline__ ushort f2b(float x) {
  __hip_bfloat16 h = __float2bfloat16(x);
  return *reinterpret_cast<const ushort*>(&h);
}

// C[row, col] = sum_k A[row*512+k] * W[k*512+col]   (all fp32)
__global__ __launch_bounds__(256) void proj_kernel(
    const float* __restrict__ A, const float* __restrict__ W, float* __restrict__ C) {
  __shared__ float arow[512];
  const int row = blockIdx.y;
  const int col = blockIdx.x * 256 + threadIdx.x;
  for (int e = threadIdx.x; e < 512; e += 256) arow[e] = A[(size_t)row * 512 + e];
  __syncthreads();
  float acc = 0.f;
#pragma unroll 8
  for (int e = 0; e < 512; ++e) acc += arow[e] * W[(size_t)e * 512 + col];
  C[(size_t)row * 512 + col] = acc;
}

// Flash-style MFMA attention. Block = 256 thr (4 waves), Q-tile 64 rows per (b,h).
__global__ __launch_bounds__(256) void flash_attn_kernel(
    const float* __restrict__ Qp, const float* __restrict__ Kp,
    const float* __restrict__ Vp, const int* __restrict__ mask,
    float* __restrict__ Op) {
  __shared__ __align__(16) ushort Qs[64][LDK];  // [q][d]
  __shared__ __align__(16) ushort Ks[64][LDK];  // [k][d]
  __shared__ __align__(16) ushort Vt[64][LDK];  // [d][k]  (transposed on store)
  __shared__ __align__(16) ushort Ps[64][LDK];  // [q][k]  P round-trip C->A layout

  const int bid = blockIdx.x;
  const int qt = bid & 31;
  const int h  = (bid >> 5) & 7;
  const int b  = bid >> 8;
  const int q0 = qt * 64;
  const int tid  = threadIdx.x;
  const int lane = tid & 63;
  const int w    = tid >> 6;
  const int col  = lane & 15;   // MFMA n / C-col
  const int quad = lane >> 4;   // MFMA k-group / C-row-group

  // stage Q tile (64 q x 64 d) as bf16
#pragma unroll 4
  for (int it = 0; it < 16; ++it) {
    int idx = it * 256 + tid;
    int qq = idx >> 6, d = idx & 63;
    Qs[qq][d] = f2b(Qp[(size_t)(b * S + q0 + qq) * HD + h * D + d]);
  }
  __syncthreads();

  f32x4 oacc[4];
  float m[4], l[4];
#pragma unroll
  for (int c = 0; c < 4; ++c) oacc[c] = f32x4{0.f, 0.f, 0.f, 0.f};
#pragma unroll
  for (int r = 0; r < 4; ++r) { m[r] = -INFINITY; l[r] = 0.f; }

  for (int kt = 0; kt < 32; ++kt) {
    const int k0 = kt * 64;
    // stage K (as-is) and V (transposed) tiles
#pragma unroll 4
    for (int it = 0; it < 16; ++it) {
      int idx = it * 256 + tid;
      int kk = idx >> 6, d = idx & 63;
      size_t g = ((size_t)(b * S + k0 + kk) * H + h) * D + d;
      Ks[kk][d] = f2b(Kp[g]);
      Vt[d][kk] = f2b(Vp[g]);
    }
    __syncthreads();

    // mask tile: lane's 16 score positions
    int mk[4][4];
    {
      const int* mp = mask + (size_t)(b * S + q0 + w * 16 + quad * 4) * S + k0 + col;
#pragma unroll
      for (int r = 0; r < 4; ++r)
#pragma unroll
        for (int c = 0; c < 4; ++c) mk[r][c] = mp[(size_t)r * S + c * 16];
    }

    // QK^T: 16 q-rows x 64 keys per wave
    f32x4 sc[4];
#pragma unroll
    for (int c = 0; c < 4; ++c) sc[c] = f32x4{0.f, 0.f, 0.f, 0.f};
    bf16x8 a0 = *(const bf16x8*)&Qs[w * 16 + col][quad * 8];
    bf16x8 a1 = *(const bf16x8*)&Qs[w * 16 + col][32 + quad * 8];
#pragma unroll
    for (int c = 0; c < 4; ++c) {
      bf16x8 kb0 = *(const bf16x8*)&Ks[c * 16 + col][quad * 8];
      bf16x8 kb1 = *(const bf16x8*)&Ks[c * 16 + col][32 + quad * 8];
      sc[c] = __builtin_amdgcn_mfma_f32_16x16x32_bf16(a0, kb0, sc[c], 0, 0, 0);
      sc[c] = __builtin_amdgcn_mfma_f32_16x16x32_bf16(a1, kb1, sc[c], 0, 0, 0);
    }

    // mask + scale + online softmax (per q-row = quad*4+r)
    float tmax[4] = {-INFINITY, -INFINITY, -INFINITY, -INFINITY};
#pragma unroll
    for (int c = 0; c < 4; ++c)
#pragma unroll
      for (int r = 0; r < 4; ++r) {
        float s = mk[r][c] ? NEG : sc[c][r] * SCALE;
        sc[c][r] = s;
        tmax[r] = fmaxf(tmax[r], s);
      }
#pragma unroll
    for (int r = 0; r < 4; ++r)
#pragma unroll
      for (int off = 1; off < 16; off <<= 1)
        tmax[r] = fmaxf(tmax[r], __shfl_xor(tmax[r], off));

    float al[4], rs[4];
#pragma unroll
    for (int r = 0; r < 4; ++r) {
      float mn = fmaxf(m[r], tmax[r]);
      al[r] = __expf(m[r] - mn);
      m[r] = mn;
      rs[r] = 0.f;
    }
#pragma unroll
    for (int c = 0; c < 4; ++c)
#pragma unroll
      for (int r = 0; r < 4; ++r) {
        float p = __expf(sc[c][r] - m[r]);
        sc[c][r] = p;
        rs[r] += p;
      }
#pragma unroll
    for (int r = 0; r < 4; ++r) {
#pragma unroll
      for (int off = 1; off < 16; off <<= 1) rs[r] += __shfl_xor(rs[r], off);
      l[r] = l[r] * al[r] + rs[r];
    }
#pragma unroll
    for (int c = 0; c < 4; ++c)
#pragma unroll
      for (int r = 0; r < 4; ++r) oacc[c][r] *= al[r];

    // P: C-layout -> LDS -> A-layout (wave-private rows)
#pragma unroll
    for (int r = 0; r < 4; ++r)
#pragma unroll
      for (int c = 0; c < 4; ++c)
        Ps[w * 16 + quad * 4 + r][c * 16 + col] = f2b(sc[c][r]);
    __threadfence_block();  // order LDS write -> read within the wave

    bf16x8 pa0 = *(const bf16x8*)&Ps[w * 16 + col][quad * 8];
    bf16x8 pa1 = *(const bf16x8*)&Ps[w * 16 + col][32 + quad * 8];
#pragma unroll
    for (int c = 0; c < 4; ++c) {
      bf16x8 vb0 = *(const bf16x8*)&Vt[c * 16 + col][quad * 8];
      bf16x8 vb1 = *(const bf16x8*)&Vt[c * 16 + col][32 + quad * 8];
      oacc[c] = __builtin_amdgcn_mfma_f32_16x16x32_bf16(pa0, vb0, oacc[c], 0, 0, 0);
      oacc[c] = __builtin_amdgcn_mfma_f32_16x16x32_bf16(pa1, vb1, oacc[c], 0, 0, 0);
    }
    __syncthreads();  // before next-iter staging overwrites Ks/Vt
  }

  float inv[4];
#pragma unroll
  for (int r = 0; r < 4; ++r) inv[r] = 1.f / l[r];
#pragma unroll
  for (int c = 0; c < 4; ++c)
#pragma unroll
    for (int r = 0; r < 4; ++r)
      Op[(size_t)(b * S + q0 + w * 16 + quad * 4 + r) * HD + h * D + c * 16 + col] =
          oacc[c][r] * inv[r];
}

}  // namespace

extern "C" void kernel_launch(void* const* d_in, const int* in_sizes, int n_in,
                              void* d_out, int out_size, void* d_ws, size_t ws_size,
                              hipStream_t stream) {
  const float* inputs = (const float*)d_in[0];   // (B,S,E)
  const float* keys   = (const float*)d_in[1];   // (B,S,H,D)
  const float* values = (const float*)d_in[2];   // (B,S,H,D)
  const float* wq     = (const float*)d_in[3];   // (E, HD)
  const float* wo     = (const float*)d_in[4];   // (HD, E)
  const int*   maskp  = (const int*)d_in[5];     // (B,S,S) bool as int32
  float* out = (float*)d_out;                    // (B,S,E)

  float* Qf   = (float*)d_ws;                    // B*S*HD fp32 = 8 MB
  float* attn = Qf + (size_t)B * S * HD;         // B*S*HD fp32 = 8 MB

  dim3 blk(256);
  proj_kernel<<<dim3(HD / 256, B * S), blk, 0, stream>>>(inputs, wq, Qf);
  flash_attn_kernel<<<dim3(B * H * (S / 64)), blk, 0, stream>>>(Qf, keys, values, maskp, attn);
  proj_kernel<<<dim3(E / 256, B * S), blk, 0, stream>>>(attn, wo, out);
}

// Round 5
// 267.448 us; speedup vs baseline: 23.0936x; 1.8544x over previous
//
#include <hip/hip_runtime.h>
#include <hip/hip_bf16.h>

namespace {

constexpr int B = 2, S = 2048, E = 512, H = 8, D = 64, HD = 512;
constexpr float NEG = -1e10f;
constexpr float SCALE = 0.125f;  // 1/sqrt(64)
constexpr int LDK = 72;          // flash: padded row stride (bf16)
constexpr int PLD = 40;          // proj: padded row stride (bf16), 80 B = 16B-aligned

typedef __attribute__((ext_vector_type(8))) short bf16x8;
typedef __attribute__((ext_vector_type(4))) float f32x4;
typedef __attribute__((ext_vector_type(4))) float float4v;

__device__ __forceinline__ ushort f2b(float x) {
  __hip_bfloat16 h = __float2bfloat16(x);
  return *reinterpret_cast<const ushort*>(&h);
}
__device__ __forceinline__ float b2f_u(ushort u) {
  __hip_bfloat16 h = *reinterpret_cast<const __hip_bfloat16*>(&u);
  return __bfloat162float(h);
}

// ---------------------------------------------------------------------------
// MFMA split-bf16 GEMM: C[M x 512] = A[M x 512] @ W[512 x 512], fp32 in/out.
// Block tile 64x64, BK=32, 4 waves -> each wave 32x32 (2x2 MFMA tiles).
// A split into bf16 hi+lo (2 MFMA products) => A-side error ~2^-17; W plain bf16.
__global__ __launch_bounds__(256) void proj_mfma_kernel(
    const float* __restrict__ A, const float* __restrict__ Wg, float* __restrict__ C) {
  __shared__ __align__(16) ushort As_hi[64][PLD];
  __shared__ __align__(16) ushort As_lo[64][PLD];
  __shared__ __align__(16) ushort Ws[64][PLD];   // [n][k] transposed

  const int tid  = threadIdx.x;
  const int lane = tid & 63;
  const int w    = tid >> 6;
  const int col  = lane & 15;
  const int quad = lane >> 4;
  const int m0 = blockIdx.y * 64;
  const int n0 = blockIdx.x * 64;
  const int wm = (w & 1) * 32;
  const int wn = (w >> 1) * 32;

  const int ar = tid >> 2;          // A stage: row 0..63
  const int ak = (tid & 3) * 8;     // k offset 0,8,16,24
  const int wn_s = tid & 63;        // W stage: n
  const int wk_s = tid >> 6;        // W stage: k base 0..3

  f32x4 acc[2][2];
#pragma unroll
  for (int i = 0; i < 2; ++i)
#pragma unroll
    for (int j = 0; j < 2; ++j) acc[i][j] = f32x4{0.f, 0.f, 0.f, 0.f};

  for (int kt = 0; kt < 16; ++kt) {
    const int k0 = kt * 32;
    // stage A (64 x 32) as hi/lo bf16
    {
      const float* Ap = A + (size_t)(m0 + ar) * 512 + k0 + ak;
      float4v v0 = *(const float4v*)Ap;
      float4v v1 = *(const float4v*)(Ap + 4);
      float a[8] = {v0.x, v0.y, v0.z, v0.w, v1.x, v1.y, v1.z, v1.w};
      union { ushort u[8]; bf16x8 v; } hi, lo;
#pragma unroll
      for (int j = 0; j < 8; ++j) {
        ushort h = f2b(a[j]);
        hi.u[j] = h;
        lo.u[j] = f2b(a[j] - b2f_u(h));
      }
      *(bf16x8*)&As_hi[ar][ak] = hi.v;
      *(bf16x8*)&As_lo[ar][ak] = lo.v;
    }
    // stage W (32 x 64) transposed -> Ws[n][k]
#pragma unroll
    for (int p = 0; p < 8; ++p) {
      int k = p * 4 + wk_s;
      Ws[wn_s][k] = f2b(Wg[(size_t)(k0 + k) * 512 + n0 + wn_s]);
    }
    __syncthreads();

    bf16x8 ah[2], al[2], wb[2];
#pragma unroll
    for (int i = 0; i < 2; ++i) {
      ah[i] = *(const bf16x8*)&As_hi[wm + i * 16 + col][quad * 8];
      al[i] = *(const bf16x8*)&As_lo[wm + i * 16 + col][quad * 8];
    }
#pragma unroll
    for (int j = 0; j < 2; ++j)
      wb[j] = *(const bf16x8*)&Ws[wn + j * 16 + col][quad * 8];
#pragma unroll
    for (int i = 0; i < 2; ++i)
#pragma unroll
      for (int j = 0; j < 2; ++j) {
        acc[i][j] = __builtin_amdgcn_mfma_f32_16x16x32_bf16(ah[i], wb[j], acc[i][j], 0, 0, 0);
        acc[i][j] = __builtin_amdgcn_mfma_f32_16x16x32_bf16(al[i], wb[j], acc[i][j], 0, 0, 0);
      }
    __syncthreads();
  }

#pragma unroll
  for (int i = 0; i < 2; ++i)
#pragma unroll
    for (int j = 0; j < 2; ++j)
#pragma unroll
      for (int r = 0; r < 4; ++r)
        C[(size_t)(m0 + wm + i * 16 + quad * 4 + r) * 512 + n0 + wn + j * 16 + col] =
            acc[i][j][r];
}

// ---------------------------------------------------------------------------
// Flash-style MFMA attention (unchanged from round 4).
__global__ __launch_bounds__(256) void flash_attn_kernel(
    const float* __restrict__ Qp, const float* __restrict__ Kp,
    const float* __restrict__ Vp, const int* __restrict__ mask,
    float* __restrict__ Op) {
  __shared__ __align__(16) ushort Qs[64][LDK];
  __shared__ __align__(16) ushort Ks[64][LDK];
  __shared__ __align__(16) ushort Vt[64][LDK];
  __shared__ __align__(16) ushort Ps[64][LDK];

  const int bid = blockIdx.x;
  const int qt = bid & 31;
  const int h  = (bid >> 5) & 7;
  const int b  = bid >> 8;
  const int q0 = qt * 64;
  const int tid  = threadIdx.x;
  const int lane = tid & 63;
  const int w    = tid >> 6;
  const int col  = lane & 15;
  const int quad = lane >> 4;

#pragma unroll 4
  for (int it = 0; it < 16; ++it) {
    int idx = it * 256 + tid;
    int qq = idx >> 6, d = idx & 63;
    Qs[qq][d] = f2b(Qp[(size_t)(b * S + q0 + qq) * HD + h * D + d]);
  }
  __syncthreads();

  f32x4 oacc[4];
  float m[4], l[4];
#pragma unroll
  for (int c = 0; c < 4; ++c) oacc[c] = f32x4{0.f, 0.f, 0.f, 0.f};
#pragma unroll
  for (int r = 0; r < 4; ++r) { m[r] = -INFINITY; l[r] = 0.f; }

  for (int kt = 0; kt < 32; ++kt) {
    const int k0 = kt * 64;
#pragma unroll 4
    for (int it = 0; it < 16; ++it) {
      int idx = it * 256 + tid;
      int kk = idx >> 6, d = idx & 63;
      size_t g = ((size_t)(b * S + k0 + kk) * H + h) * D + d;
      Ks[kk][d] = f2b(Kp[g]);
      Vt[d][kk] = f2b(Vp[g]);
    }
    __syncthreads();

    int mk[4][4];
    {
      const int* mp = mask + (size_t)(b * S + q0 + w * 16 + quad * 4) * S + k0 + col;
#pragma unroll
      for (int r = 0; r < 4; ++r)
#pragma unroll
        for (int c = 0; c < 4; ++c) mk[r][c] = mp[(size_t)r * S + c * 16];
    }

    f32x4 sc[4];
#pragma unroll
    for (int c = 0; c < 4; ++c) sc[c] = f32x4{0.f, 0.f, 0.f, 0.f};
    bf16x8 a0 = *(const bf16x8*)&Qs[w * 16 + col][quad * 8];
    bf16x8 a1 = *(const bf16x8*)&Qs[w * 16 + col][32 + quad * 8];
#pragma unroll
    for (int c = 0; c < 4; ++c) {
      bf16x8 kb0 = *(const bf16x8*)&Ks[c * 16 + col][quad * 8];
      bf16x8 kb1 = *(const bf16x8*)&Ks[c * 16 + col][32 + quad * 8];
      sc[c] = __builtin_amdgcn_mfma_f32_16x16x32_bf16(a0, kb0, sc[c], 0, 0, 0);
      sc[c] = __builtin_amdgcn_mfma_f32_16x16x32_bf16(a1, kb1, sc[c], 0, 0, 0);
    }

    float tmax[4] = {-INFINITY, -INFINITY, -INFINITY, -INFINITY};
#pragma unroll
    for (int c = 0; c < 4; ++c)
#pragma unroll
      for (int r = 0; r < 4; ++r) {
        float s = mk[r][c] ? NEG : sc[c][r] * SCALE;
        sc[c][r] = s;
        tmax[r] = fmaxf(tmax[r], s);
      }
#pragma unroll
    for (int r = 0; r < 4; ++r)
#pragma unroll
      for (int off = 1; off < 16; off <<= 1)
        tmax[r] = fmaxf(tmax[r], __shfl_xor(tmax[r], off));

    float al[4], rs[4];
#pragma unroll
    for (int r = 0; r < 4; ++r) {
      float mn = fmaxf(m[r], tmax[r]);
      al[r] = __expf(m[r] - mn);
      m[r] = mn;
      rs[r] = 0.f;
    }
#pragma unroll
    for (int c = 0; c < 4; ++c)
#pragma unroll
      for (int r = 0; r < 4; ++r) {
        float p = __expf(sc[c][r] - m[r]);
        sc[c][r] = p;
        rs[r] += p;
      }
#pragma unroll
    for (int r = 0; r < 4; ++r) {
#pragma unroll
      for (int off = 1; off < 16; off <<= 1) rs[r] += __shfl_xor(rs[r], off);
      l[r] = l[r] * al[r] + rs[r];
    }
#pragma unroll
    for (int c = 0; c < 4; ++c)
#pragma unroll
      for (int r = 0; r < 4; ++r) oacc[c][r] *= al[r];

#pragma unroll
    for (int r = 0; r < 4; ++r)
#pragma unroll
      for (int c = 0; c < 4; ++c)
        Ps[w * 16 + quad * 4 + r][c * 16 + col] = f2b(sc[c][r]);
    __threadfence_block();

    bf16x8 pa0 = *(const bf16x8*)&Ps[w * 16 + col][quad * 8];
    bf16x8 pa1 = *(const bf16x8*)&Ps[w * 16 + col][32 + quad * 8];
#pragma unroll
    for (int c = 0; c < 4; ++c) {
      bf16x8 vb0 = *(const bf16x8*)&Vt[c * 16 + col][quad * 8];
      bf16x8 vb1 = *(const bf16x8*)&Vt[c * 16 + col][32 + quad * 8];
      oacc[c] = __builtin_amdgcn_mfma_f32_16x16x32_bf16(pa0, vb0, oacc[c], 0, 0, 0);
      oacc[c] = __builtin_amdgcn_mfma_f32_16x16x32_bf16(pa1, vb1, oacc[c], 0, 0, 0);
    }
    __syncthreads();
  }

  float inv[4];
#pragma unroll
  for (int r = 0; r < 4; ++r) inv[r] = 1.f / l[r];
#pragma unroll
  for (int c = 0; c < 4; ++c)
#pragma unroll
    for (int r = 0; r < 4; ++r)
      Op[(size_t)(b * S + q0 + w * 16 + quad * 4 + r) * HD + h * D + c * 16 + col] =
          oacc[c][r] * inv[r];
}

}  // namespace

extern "C" void kernel_launch(void* const* d_in, const int* in_sizes, int n_in,
                              void* d_out, int out_size, void* d_ws, size_t ws_size,
                              hipStream_t stream) {
  const float* inputs = (const float*)d_in[0];   // (B,S,E)
  const float* keys   = (const float*)d_in[1];   // (B,S,H,D)
  const float* values = (const float*)d_in[2];   // (B,S,H,D)
  const float* wq     = (const float*)d_in[3];   // (E, HD)
  const float* wo     = (const float*)d_in[4];   // (HD, E)
  const int*   maskp  = (const int*)d_in[5];     // (B,S,S) bool as int32
  float* out = (float*)d_out;                    // (B,S,E)

  float* Qf   = (float*)d_ws;                    // B*S*HD fp32 = 8 MB
  float* attn = Qf + (size_t)B * S * HD;         // B*S*HD fp32 = 8 MB

  dim3 blk(256);
  proj_mfma_kernel<<<dim3(8, 64), blk, 0, stream>>>(inputs, wq, Qf);
  flash_attn_kernel<<<dim3(B * H * (S / 64)), blk, 0, stream>>>(Qf, keys, values, maskp, attn);
  proj_mfma_kernel<<<dim3(8, 64), blk, 0, stream>>>(attn, wo, out);
}

// Round 6
// 193.826 us; speedup vs baseline: 31.8652x; 1.3798x over previous
//
#include <hip/hip_runtime.h>
#include <hip/hip_bf16.h>

namespace {

constexpr int B = 2, S = 2048, E = 512, H = 8, D = 64, HD = 512;
constexpr float NEG = -1e10f;
constexpr float SCALE = 0.125f;  // 1/sqrt(64)
constexpr int LDK = 72;   // d-dim rows (64+8 pad), 144 B
constexpr int LDV = 136;  // k-dim rows (128+8 pad), 272 B
constexpr int PLD = 40;   // proj LDS row stride (bf16)

typedef __attribute__((ext_vector_type(8))) short bf16x8;
typedef __attribute__((ext_vector_type(4))) unsigned short u16x4;
typedef __attribute__((ext_vector_type(4))) float f32x4;
typedef __attribute__((ext_vector_type(4))) float float4v;

__device__ __forceinline__ ushort f2b(float x) {
  __hip_bfloat16 h = __float2bfloat16(x);
  return *reinterpret_cast<const ushort*>(&h);
}
__device__ __forceinline__ float b2f_u(ushort u) {
  __hip_bfloat16 h = *reinterpret_cast<const __hip_bfloat16*>(&u);
  return __bfloat162float(h);
}

// ---------------------------------------------------------------------------
// Prep: K (b,k,h,d) fp32 -> Kbf (b,h,k,d) bf16 ; V (b,k,h,d) fp32 -> Vtbf (b,h,d,k) bf16.
// One block per (b,h,64-key tile); V transposed through LDS.
__global__ __launch_bounds__(256) void prep_kv_kernel(
    const float* __restrict__ K, const float* __restrict__ V,
    ushort* __restrict__ Kbf, ushort* __restrict__ Vtbf) {
  __shared__ ushort Vn[64][76];
  const int bid = blockIdx.x;
  const int kt = bid & 31;
  const int bh = bid >> 5;
  const int b = bh >> 3, h = bh & 7;
  const int k0 = kt * 64;
  const int t = threadIdx.x;
#pragma unroll
  for (int i = 0; i < 4; ++i) {
    int c = i * 256 + t;
    int kk = c >> 4, d4 = (c & 15) * 4;
    size_t g = ((size_t)(b * 2048 + k0 + kk) * 8 + h) * 64 + d4;
    float4v kv = *(const float4v*)(K + g);
    float4v vv = *(const float4v*)(V + g);
    u16x4 kp = {f2b(kv.x), f2b(kv.y), f2b(kv.z), f2b(kv.w)};
    u16x4 vp = {f2b(vv.x), f2b(vv.y), f2b(vv.z), f2b(vv.w)};
    *(u16x4*)(Kbf + ((size_t)(bh * 2048 + k0 + kk)) * 64 + d4) = kp;
    *(u16x4*)&Vn[kk][d4] = vp;
  }
  __syncthreads();
#pragma unroll
  for (int i = 0; i < 2; ++i) {
    int c = i * 256 + t;
    int kc8 = (c & 7) * 8, d = c >> 3;
    union { ushort u[8]; bf16x8 v; } p;
#pragma unroll
    for (int j = 0; j < 8; ++j) p.u[j] = Vn[kc8 + j][d];
    *(bf16x8*)(Vtbf + ((size_t)(bh * 64 + d)) * 2048 + k0 + kc8) = p.v;
  }
}

// ---------------------------------------------------------------------------
// proj_q: Qbf[b][h][q][d] (bf16) = inputs[M x 512] @ Wq[512 x 512]; A fp32 hi/lo split.
__global__ __launch_bounds__(256) void proj_q_kernel(
    const float* __restrict__ A, const float* __restrict__ Wg, ushort* __restrict__ Qbf) {
  __shared__ __align__(16) ushort As_hi[64][PLD];
  __shared__ __align__(16) ushort As_lo[64][PLD];
  __shared__ __align__(16) ushort Ws[64][PLD];

  const int tid = threadIdx.x;
  const int lane = tid & 63;
  const int w = tid >> 6;
  const int col = lane & 15;
  const int quad = lane >> 4;
  const int m0 = blockIdx.y * 64;
  const int n0 = blockIdx.x * 64;
  const int wm = (w & 1) * 32;
  const int wn = (w >> 1) * 32;
  const int ar = tid >> 2;
  const int ak = (tid & 3) * 8;
  const int wn_s = tid & 63;
  const int wk_s = tid >> 6;

  f32x4 acc[2][2];
#pragma unroll
  for (int i = 0; i < 2; ++i)
#pragma unroll
    for (int j = 0; j < 2; ++j) acc[i][j] = f32x4{0.f, 0.f, 0.f, 0.f};

  for (int kt = 0; kt < 16; ++kt) {
    const int k0 = kt * 32;
    {
      const float* Ap = A + (size_t)(m0 + ar) * 512 + k0 + ak;
      float4v v0 = *(const float4v*)Ap;
      float4v v1 = *(const float4v*)(Ap + 4);
      float a[8] = {v0.x, v0.y, v0.z, v0.w, v1.x, v1.y, v1.z, v1.w};
      union { ushort u[8]; bf16x8 v; } hi, lo;
#pragma unroll
      for (int j = 0; j < 8; ++j) {
        ushort hh = f2b(a[j]);
        hi.u[j] = hh;
        lo.u[j] = f2b(a[j] - b2f_u(hh));
      }
      *(bf16x8*)&As_hi[ar][ak] = hi.v;
      *(bf16x8*)&As_lo[ar][ak] = lo.v;
    }
#pragma unroll
    for (int p = 0; p < 8; ++p) {
      int k = p * 4 + wk_s;
      Ws[wn_s][k] = f2b(Wg[(size_t)(k0 + k) * 512 + n0 + wn_s]);
    }
    __syncthreads();

    bf16x8 ah[2], al[2], wb[2];
#pragma unroll
    for (int i = 0; i < 2; ++i) {
      ah[i] = *(const bf16x8*)&As_hi[wm + i * 16 + col][quad * 8];
      al[i] = *(const bf16x8*)&As_lo[wm + i * 16 + col][quad * 8];
    }
#pragma unroll
    for (int j = 0; j < 2; ++j)
      wb[j] = *(const bf16x8*)&Ws[wn + j * 16 + col][quad * 8];
#pragma unroll
    for (int i = 0; i < 2; ++i)
#pragma unroll
      for (int j = 0; j < 2; ++j) {
        acc[i][j] = __builtin_amdgcn_mfma_f32_16x16x32_bf16(ah[i], wb[j], acc[i][j], 0, 0, 0);
        acc[i][j] = __builtin_amdgcn_mfma_f32_16x16x32_bf16(al[i], wb[j], acc[i][j], 0, 0, 0);
      }
    __syncthreads();
  }

#pragma unroll
  for (int i = 0; i < 2; ++i)
#pragma unroll
    for (int j = 0; j < 2; ++j)
#pragma unroll
      for (int r = 0; r < 4; ++r) {
        int m = m0 + wm + i * 16 + quad * 4 + r;
        int n = n0 + wn + j * 16 + col;
        int b = m >> 11, q = m & 2047, h = n >> 6, dd = n & 63;
        Qbf[((size_t)(b * 8 + h) * 2048 + q) * 64 + dd] = f2b(acc[i][j][r]);
      }
}

// ---------------------------------------------------------------------------
// proj_out: out fp32 = attnb (bf16, M x 512) @ Wo[512 x 512].
__global__ __launch_bounds__(256) void proj_out_kernel(
    const ushort* __restrict__ A, const float* __restrict__ Wg, float* __restrict__ C) {
  __shared__ __align__(16) ushort As[64][PLD];
  __shared__ __align__(16) ushort Ws[64][PLD];

  const int tid = threadIdx.x;
  const int lane = tid & 63;
  const int w = tid >> 6;
  const int col = lane & 15;
  const int quad = lane >> 4;
  const int m0 = blockIdx.y * 64;
  const int n0 = blockIdx.x * 64;
  const int wm = (w & 1) * 32;
  const int wn = (w >> 1) * 32;
  const int ar = tid >> 2;
  const int ak = (tid & 3) * 8;
  const int wn_s = tid & 63;
  const int wk_s = tid >> 6;

  f32x4 acc[2][2];
#pragma unroll
  for (int i = 0; i < 2; ++i)
#pragma unroll
    for (int j = 0; j < 2; ++j) acc[i][j] = f32x4{0.f, 0.f, 0.f, 0.f};

  for (int kt = 0; kt < 16; ++kt) {
    const int k0 = kt * 32;
    *(bf16x8*)&As[ar][ak] = *(const bf16x8*)(A + (size_t)(m0 + ar) * 512 + k0 + ak);
#pragma unroll
    for (int p = 0; p < 8; ++p) {
      int k = p * 4 + wk_s;
      Ws[wn_s][k] = f2b(Wg[(size_t)(k0 + k) * 512 + n0 + wn_s]);
    }
    __syncthreads();

    bf16x8 ah[2], wb[2];
#pragma unroll
    for (int i = 0; i < 2; ++i)
      ah[i] = *(const bf16x8*)&As[wm + i * 16 + col][quad * 8];
#pragma unroll
    for (int j = 0; j < 2; ++j)
      wb[j] = *(const bf16x8*)&Ws[wn + j * 16 + col][quad * 8];
#pragma unroll
    for (int i = 0; i < 2; ++i)
#pragma unroll
      for (int j = 0; j < 2; ++j)
        acc[i][j] = __builtin_amdgcn_mfma_f32_16x16x32_bf16(ah[i], wb[j], acc[i][j], 0, 0, 0);
    __syncthreads();
  }

#pragma unroll
  for (int i = 0; i < 2; ++i)
#pragma unroll
    for (int j = 0; j < 2; ++j)
#pragma unroll
      for (int r = 0; r < 4; ++r)
        C[(size_t)(m0 + wm + i * 16 + quad * 4 + r) * 512 + n0 + wn + j * 16 + col] =
            acc[i][j][r];
}

// ---------------------------------------------------------------------------
// Flash attention, all-bf16 staging, K-tile = 128 keys.
__global__ __launch_bounds__(256) void flash_attn_kernel(
    const ushort* __restrict__ Qbf, const ushort* __restrict__ Kbf,
    const ushort* __restrict__ Vtbf, const int* __restrict__ mask,
    ushort* __restrict__ Op) {
  __shared__ __align__(16) ushort Qs[64][LDK];
  __shared__ __align__(16) ushort Ks[128][LDK];
  __shared__ __align__(16) ushort Vt[64][LDV];
  __shared__ __align__(16) ushort Ps[64][LDV];

  const int bid = blockIdx.x;
  const int qt = bid & 31;
  const int bh = bid >> 5;       // b*8 + h
  const int b = bh >> 3, h = bh & 7;
  const int q0 = qt * 64;
  const int tid = threadIdx.x;
  const int lane = tid & 63;
  const int w = tid >> 6;
  const int col = lane & 15;
  const int quad = lane >> 4;

  // stage Q (contiguous 64x64 bf16)
  const ushort* Qt = Qbf + (size_t)(bh * 2048 + q0) * 64;
#pragma unroll
  for (int i = 0; i < 2; ++i) {
    int c = i * 256 + tid;
    *(bf16x8*)&Qs[c >> 3][(c & 7) * 8] = *(const bf16x8*)(Qt + c * 8);
  }
  __syncthreads();

  f32x4 oacc[4];
  float m[4], l[4];
#pragma unroll
  for (int c = 0; c < 4; ++c) oacc[c] = f32x4{0.f, 0.f, 0.f, 0.f};
#pragma unroll
  for (int r = 0; r < 4; ++r) { m[r] = -INFINITY; l[r] = 0.f; }

  const bf16x8 a0 = *(const bf16x8*)&Qs[w * 16 + col][quad * 8];
  const bf16x8 a1 = *(const bf16x8*)&Qs[w * 16 + col][32 + quad * 8];

  for (int kt = 0; kt < 16; ++kt) {
    const int k0 = kt * 128;
    // stage K tile (128x64, contiguous) and Vt tile (64x128, rows stride 2048)
    const ushort* Ktile = Kbf + (size_t)(bh * 2048 + k0) * 64;
    const ushort* Vtile = Vtbf + (size_t)(bh * 64) * 2048 + k0;
#pragma unroll
    for (int i = 0; i < 4; ++i) {
      int c = i * 256 + tid;
      *(bf16x8*)&Ks[c >> 3][(c & 7) * 8] = *(const bf16x8*)(Ktile + c * 8);
      int d = c >> 4, k8 = (c & 15) * 8;
      *(bf16x8*)&Vt[d][k8] = *(const bf16x8*)(Vtile + (size_t)d * 2048 + k8);
    }
    __syncthreads();

    int mk[4][8];
    {
      const int* mp = mask + (size_t)(b * S + q0 + w * 16 + quad * 4) * S + k0 + col;
#pragma unroll
      for (int r = 0; r < 4; ++r)
#pragma unroll
        for (int c = 0; c < 8; ++c) mk[r][c] = mp[(size_t)r * S + c * 16];
    }

    // QK^T: 16 q-rows x 128 keys per wave
    f32x4 sc[8];
#pragma unroll
    for (int c = 0; c < 8; ++c) sc[c] = f32x4{0.f, 0.f, 0.f, 0.f};
#pragma unroll
    for (int c = 0; c < 8; ++c) {
      bf16x8 kb0 = *(const bf16x8*)&Ks[c * 16 + col][quad * 8];
      bf16x8 kb1 = *(const bf16x8*)&Ks[c * 16 + col][32 + quad * 8];
      sc[c] = __builtin_amdgcn_mfma_f32_16x16x32_bf16(a0, kb0, sc[c], 0, 0, 0);
      sc[c] = __builtin_amdgcn_mfma_f32_16x16x32_bf16(a1, kb1, sc[c], 0, 0, 0);
    }

    float tmax[4] = {-INFINITY, -INFINITY, -INFINITY, -INFINITY};
#pragma unroll
    for (int c = 0; c < 8; ++c)
#pragma unroll
      for (int r = 0; r < 4; ++r) {
        float s = mk[r][c] ? NEG : sc[c][r] * SCALE;
        sc[c][r] = s;
        tmax[r] = fmaxf(tmax[r], s);
      }
#pragma unroll
    for (int r = 0; r < 4; ++r)
#pragma unroll
      for (int off = 1; off < 16; off <<= 1)
        tmax[r] = fmaxf(tmax[r], __shfl_xor(tmax[r], off));

    float al[4], rs[4];
#pragma unroll
    for (int r = 0; r < 4; ++r) {
      float mn = fmaxf(m[r], tmax[r]);
      al[r] = __expf(m[r] - mn);
      m[r] = mn;
      rs[r] = 0.f;
    }
#pragma unroll
    for (int c = 0; c < 8; ++c)
#pragma unroll
      for (int r = 0; r < 4; ++r) {
        float p = __expf(sc[c][r] - m[r]);
        sc[c][r] = p;
        rs[r] += p;
      }
#pragma unroll
    for (int r = 0; r < 4; ++r) {
#pragma unroll
      for (int off = 1; off < 16; off <<= 1) rs[r] += __shfl_xor(rs[r], off);
      l[r] = l[r] * al[r] + rs[r];
    }
#pragma unroll
    for (int c = 0; c < 4; ++c)
#pragma unroll
      for (int r = 0; r < 4; ++r) oacc[c][r] *= al[r];

    // P: C-layout -> LDS (wave-private rows)
#pragma unroll
    for (int r = 0; r < 4; ++r)
#pragma unroll
      for (int c = 0; c < 8; ++c)
        Ps[w * 16 + quad * 4 + r][c * 16 + col] = f2b(sc[c][r]);
    __threadfence_block();

    bf16x8 pa[4];
#pragma unroll
    for (int kb = 0; kb < 4; ++kb)
      pa[kb] = *(const bf16x8*)&Ps[w * 16 + col][kb * 32 + quad * 8];
#pragma unroll
    for (int c = 0; c < 4; ++c)
#pragma unroll
      for (int kb = 0; kb < 4; ++kb) {
        bf16x8 vb = *(const bf16x8*)&Vt[c * 16 + col][kb * 32 + quad * 8];
        oacc[c] = __builtin_amdgcn_mfma_f32_16x16x32_bf16(pa[kb], vb, oacc[c], 0, 0, 0);
      }
    __syncthreads();
  }

  float inv[4];
#pragma unroll
  for (int r = 0; r < 4; ++r) inv[r] = 1.f / l[r];
#pragma unroll
  for (int c = 0; c < 4; ++c)
#pragma unroll
    for (int r = 0; r < 4; ++r)
      Op[(size_t)(b * S + q0 + w * 16 + quad * 4 + r) * HD + h * D + c * 16 + col] =
          f2b(oacc[c][r] * inv[r]);
}

}  // namespace

extern "C" void kernel_launch(void* const* d_in, const int* in_sizes, int n_in,
                              void* d_out, int out_size, void* d_ws, size_t ws_size,
                              hipStream_t stream) {
  const float* inputs = (const float*)d_in[0];   // (B,S,E)
  const float* keys   = (const float*)d_in[1];   // (B,S,H,D)
  const float* values = (const float*)d_in[2];   // (B,S,H,D)
  const float* wq     = (const float*)d_in[3];   // (E, HD)
  const float* wo     = (const float*)d_in[4];   // (HD, E)
  const int*   maskp  = (const int*)d_in[5];     // (B,S,S) bool as int32
  float* out = (float*)d_out;                    // (B,S,E)

  ushort* Qbf   = (ushort*)d_ws;                 // (B,H,S,D) bf16, 4 MB
  ushort* Kbf   = Qbf + (size_t)2097152;         // (B,H,S,D) bf16, 4 MB
  ushort* Vtbf  = Kbf + (size_t)2097152;         // (B,H,D,S) bf16, 4 MB
  ushort* attnb = Vtbf + (size_t)2097152;        // (B,S,HD)  bf16, 4 MB

  dim3 blk(256);
  proj_q_kernel<<<dim3(8, 64), blk, 0, stream>>>(inputs, wq, Qbf);
  prep_kv_kernel<<<dim3(512), blk, 0, stream>>>(keys, values, Kbf, Vtbf);
  flash_attn_kernel<<<dim3(512), blk, 0, stream>>>(Qbf, Kbf, Vtbf, maskp, attnb);
  proj_out_kernel<<<dim3(8, 64), blk, 0, stream>>>(attnb, wo, out);
}